// Round 3
// baseline (331.821 us; speedup 1.0000x reference)
//
#include <hip/hip_runtime.h>
#include <hip/hip_fp16.h>
#include <math.h>

#define NPTS 200001
typedef float v2f __attribute__((ext_vector_type(2)));

// ---------------------------------------------------------------------------
// prep: blocks 0..3   : fp32 trapz partial sums for SILU_C / SIG_C
//       blocks 4..24  : build combined+scaled weights into workspace
// ---------------------------------------------------------------------------
__global__ void prep(const float* __restrict__ wss0, const float* __restrict__ wvv0,
                     const float* __restrict__ wss1, const float* __restrict__ wvv1,
                     const float* __restrict__ wsv,  const float* __restrict__ wvs,
                     float* __restrict__ partials,
                     float* __restrict__ wssc, float* __restrict__ wvvc,
                     float* __restrict__ wgc)
{
    const int b = blockIdx.x;
    const int t = threadIdx.x;
    if (b < 4) {
        float ls = 0.f, lg = 0.f;
        for (int i = b * 256 + t; i < NPTS; i += 1024) {
            float xv  = -12.0f + 24.0f * ((float)i / 200000.0f);
            float pdf = __expf(-0.5f * xv * xv) * 0.39894228040143267794f;
            float sg  = 1.0f / (1.0f + __expf(-xv));
            float si  = xv * sg;
            float wt  = (i == 0 || i == NPTS - 1) ? 0.5f : 1.0f;
            ls = fmaf(wt * si * si, pdf, ls);
            lg = fmaf(wt * sg * sg, pdf, lg);
        }
        __shared__ float r1[256], r2[256];
        r1[t] = ls; r2[t] = lg;
        __syncthreads();
        for (int st = 128; st > 0; st >>= 1) {
            if (t < st) { r1[t] += r1[t + st]; r2[t] += r2[t + st]; }
            __syncthreads();
        }
        if (t == 0) { partials[b] = r1[0]; partials[4 + b] = r2[0]; }
    } else {
        const int gid = (b - 4) * 256 + t;
        const float CSC  = (float)(0.05590169943749474241);                      // 1/sqrt(320)
        const float CSC3 = (float)(0.05590169943749474241 / 1.7320508075688772935);
        if (gid < 3264) {                       // wssc[pair(136)][24]
            int p = gid / 24, w = gid % 24;
            int u = 0, rem = p;
            while (rem >= 16 - u) { rem -= 16 - u; ++u; }
            int tt = u + rem;                   // u <= tt
            float val;
            if (w < 16) {
                val = wss0[(u * 16 + tt) * 16 + w];
                if (tt != u) val += wss0[(tt * 16 + u) * 16 + w];
            } else {
                val = wss1[(u * 16 + tt) * 8 + (w - 16)];
                if (tt != u) val += wss1[(tt * 16 + u) * 8 + (w - 16)];
            }
            wssc[gid] = CSC * val;
        } else if (gid < 4128) {                // wvvc[pair(36)][24]
            int q = gid - 3264;
            int p = q / 24, w = q % 24;
            int u = 0, rem = p;
            while (rem >= 8 - u) { rem -= 8 - u; ++u; }
            int tt = u + rem;
            float val;
            if (w < 16) {
                val = wvv0[(u * 8 + tt) * 16 + w];
                if (tt != u) val += wvv0[(tt * 8 + u) * 16 + w];
            } else {
                val = wvv1[(u * 8 + tt) * 8 + (w - 16)];
                if (tt != u) val += wvv1[(tt * 8 + u) * 8 + (w - 16)];
            }
            wvvc[q] = CSC3 * val;
        } else if (gid < 5152) {                // wgc[b(8)][a(16)][w(8)]
            int q  = gid - 4128;
            int bb = q >> 7;
            int a  = (q >> 3) & 15;
            int w  = q & 7;
            // C_V/SQRT3 = 1/16 exactly
            wgc[q] = 0.0625f * (wsv[(a * 8 + bb) * 8 + w] + wvs[(bb * 16 + a) * 8 + w]);
        }
    }
}

static __device__ __forceinline__ v2f h2v(__half2 h) {
    float2 f = __half22float2(h);
    v2f r; r.x = f.x; r.y = f.y;
    return r;
}

// ---------------------------------------------------------------------------
// Main kernel: 2 rows/thread, rows packed as half2 per component in LDS
// (lgkm domain = in-order DS only). Weights forced onto the VECTOR memory
// path (opaque VGPR zero in the address) -> global_load_dwordx4 in the vmcnt
// domain, L1-resident, fine-grained pipelined waits. Dual-row accumulators
// are float2 ext-vectors -> v_pk_fma_f32 (2 FMAs/inst).
// ---------------------------------------------------------------------------
__global__ __launch_bounds__(256) void seg_main(
    const float* __restrict__ x,
    const float* __restrict__ wssc,     // [136][24]
    const float* __restrict__ wvvc,     // [36][24]
    const float* __restrict__ wgc,      // [8][16][8]
    const float* __restrict__ partials, // [8]
    float* __restrict__ out, int n)
{
    __shared__ __half2 xs[40][256];   // 40 KB -> 4 blocks/CU
    const int tid = threadIdx.x;
    const int r0 = blockIdx.x * 512 + 2 * tid;
    const int r1 = r0 + 1;
    const int l0 = (r0 < n) ? r0 : n - 1;
    const int l1 = (r1 < n) ? r1 : n - 1;

    // ---- stage both rows into LDS as packed half2 ----
    {
        float A[40] __attribute__((aligned(16)));
        float B[40] __attribute__((aligned(16)));
        const float4* p0 = (const float4*)(x + (size_t)l0 * 40);
        const float4* p1 = (const float4*)(x + (size_t)l1 * 40);
#pragma unroll
        for (int k = 0; k < 10; ++k) { ((float4*)A)[k] = p0[k]; ((float4*)B)[k] = p1[k]; }
#pragma unroll
        for (int c = 0; c < 40; ++c) xs[c][tid] = __floats2half2_rn(A[c], B[c]);
    }
    // no __syncthreads: each thread reads only its own column

    // Opaque zero in a VGPR: forces weight addresses onto the vector path.
    int vzero;
    asm volatile("v_mov_b32 %0, 0" : "=v"(vzero));

    v2f acc[24];
#pragma unroll
    for (int w = 0; w < 24; ++w) acc[w] = (v2f)(0.f);

    // ---- s (x) s quadratic features: 136 symmetrized pairs ----
    const float4* wp4 = (const float4*)(wssc + vzero);
#pragma unroll 1
    for (int u = 0; u < 16; ++u) {
        v2f su = h2v(xs[u][tid]);
#pragma unroll 2
        for (int t2 = u; t2 < 16; ++t2) {
            v2f sv = h2v(xs[t2][tid]);
            v2f pr = su * sv;
            float wv[24] __attribute__((aligned(16)));
#pragma unroll
            for (int k = 0; k < 6; ++k) ((float4*)wv)[k] = wp4[k];
#pragma unroll
            for (int w = 0; w < 24; ++w) acc[w] = pr * wv[w] + acc[w];
            wp4 += 6;
        }
    }

    // ---- <v_u, v_t> features: 36 symmetrized pairs ----
    const float4* wq4 = (const float4*)(wvvc + vzero);
#pragma unroll 1
    for (int u = 0; u < 8; ++u) {
        v2f a0 = h2v(xs[16 + 3 * u + 0][tid]);
        v2f a1 = h2v(xs[16 + 3 * u + 1][tid]);
        v2f a2 = h2v(xs[16 + 3 * u + 2][tid]);
#pragma unroll 2
        for (int t2 = u; t2 < 8; ++t2) {
            v2f d = a0 * h2v(xs[16 + 3 * t2 + 0][tid]);
            d = a1 * h2v(xs[16 + 3 * t2 + 1][tid]) + d;
            d = a2 * h2v(xs[16 + 3 * t2 + 2][tid]) + d;
            float wv[24] __attribute__((aligned(16)));
#pragma unroll
            for (int k = 0; k < 6; ++k) ((float4*)wv)[k] = wq4[k];
#pragma unroll
            for (int w = 0; w < 24; ++w) acc[w] = d * wv[w] + acc[w];
            wq4 += 6;
        }
    }

    // ---- normalization constants (uniform scalar loads, one-time) ----
    const float dx = 24.0f / 200000.0f;
    const float silu_c = 1.0f / sqrtf((partials[0] + partials[1] + partials[2] + partials[3]) * dx);
    const float sig_c  = 1.0f / sqrtf((partials[4] + partials[5] + partials[6] + partials[7]) * dx);

    // ---- activations; store out_s early to retire acc registers ----
    float gate0[8], gate1[8];
    {
        float o0[16] __attribute__((aligned(16)));
        float o1[16] __attribute__((aligned(16)));
#pragma unroll
        for (int w = 0; w < 16; ++w) {
            float z0 = acc[w].x, z1 = acc[w].y;
            o0[w] = silu_c * z0 / (1.f + __expf(-z0));
            o1[w] = silu_c * z1 / (1.f + __expf(-z1));
        }
#pragma unroll
        for (int w = 0; w < 8; ++w) {
            gate0[w] = sig_c / (1.f + __expf(-acc[16 + w].x));
            gate1[w] = sig_c / (1.f + __expf(-acc[16 + w].y));
        }
        if (r0 < n) {
            float4* q = (float4*)(out + (size_t)r0 * 40);
#pragma unroll
            for (int k = 0; k < 4; ++k) q[k] = ((const float4*)o0)[k];
        }
        if (r1 < n) {
            float4* q = (float4*)(out + (size_t)r1 * 40);
#pragma unroll
            for (int k = 0; k < 4; ++k) q[k] = ((const float4*)o1)[k];
        }
    }

    // ---- gated[w][i] = sum_b v[b][i] * (sum_a s[a]*Wg[b][a][w]) ----
    v2f g[24];
#pragma unroll
    for (int k = 0; k < 24; ++k) g[k] = (v2f)(0.f);
    const float4* wg4 = (const float4*)(wgc + vzero);
#pragma unroll 1
    for (int b = 0; b < 8; ++b) {
        v2f vb0 = h2v(xs[16 + 3 * b + 0][tid]);
        v2f vb1 = h2v(xs[16 + 3 * b + 1][tid]);
        v2f vb2 = h2v(xs[16 + 3 * b + 2][tid]);
        const float4* wa = wg4 + b * 32;
        v2f t[8];
#pragma unroll
        for (int w = 0; w < 8; ++w) t[w] = (v2f)(0.f);
#pragma unroll
        for (int a = 0; a < 16; ++a) {
            v2f sa = h2v(xs[a][tid]);
            float wv[8] __attribute__((aligned(16)));
            ((float4*)wv)[0] = wa[2 * a];
            ((float4*)wv)[1] = wa[2 * a + 1];
#pragma unroll
            for (int w = 0; w < 8; ++w) t[w] = sa * wv[w] + t[w];
        }
#pragma unroll
        for (int w = 0; w < 8; ++w) {
            g[3 * w + 0] = t[w] * vb0 + g[3 * w + 0];
            g[3 * w + 1] = t[w] * vb1 + g[3 * w + 1];
            g[3 * w + 2] = t[w] * vb2 + g[3 * w + 2];
        }
    }

    // ---- gate and store out_v ----
    {
        float o0[24] __attribute__((aligned(16)));
        float o1[24] __attribute__((aligned(16)));
#pragma unroll
        for (int w = 0; w < 8; ++w) {
#pragma unroll
            for (int i = 0; i < 3; ++i) {
                o0[3 * w + i] = gate0[w] * g[3 * w + i].x;
                o1[3 * w + i] = gate1[w] * g[3 * w + i].y;
            }
        }
        if (r0 < n) {
            float4* q = (float4*)(out + (size_t)r0 * 40 + 16);
#pragma unroll
            for (int k = 0; k < 6; ++k) q[k] = ((const float4*)o0)[k];
        }
        if (r1 < n) {
            float4* q = (float4*)(out + (size_t)r1 * 40 + 16);
#pragma unroll
            for (int k = 0; k < 6; ++k) q[k] = ((const float4*)o1)[k];
        }
    }
}

// ---------------------------------------------------------------------------
extern "C" void kernel_launch(void* const* d_in, const int* in_sizes, int n_in,
                              void* d_out, int out_size, void* d_ws, size_t ws_size,
                              hipStream_t stream)
{
    (void)n_in; (void)out_size; (void)ws_size;
    const float* x    = (const float*)d_in[0];
    const float* wss0 = (const float*)d_in[1];
    const float* wvv0 = (const float*)d_in[2];
    const float* wss1 = (const float*)d_in[3];
    const float* wvv1 = (const float*)d_in[4];
    const float* wsv  = (const float*)d_in[5];
    const float* wvs  = (const float*)d_in[6];
    float* out = (float*)d_out;
    const int n = in_sizes[0] / 40;

    char* ws = (char*)d_ws;
    float* partials = (float*)(ws + 0);        // 8 floats
    float* wssc     = (float*)(ws + 4096);     // 3264 floats
    float* wvvc     = (float*)(ws + 17408);    // 864 floats
    float* wgc      = (float*)(ws + 21504);    // 1024 floats

    hipLaunchKernelGGL(prep, dim3(25), dim3(256), 0, stream,
                       wss0, wvv0, wss1, wvv1, wsv, wvs, partials, wssc, wvvc, wgc);
    hipLaunchKernelGGL(seg_main, dim3((n + 511) / 512), dim3(256), 0, stream,
                       x, wssc, wvvc, wgc, partials, out, n);
}

// Round 4
// 216.669 us; speedup vs baseline: 1.5315x; 1.5315x over previous
//
#include <hip/hip_runtime.h>
#include <math.h>

#define NPTS 200001

typedef _Float16 f16;
typedef f16 f16x2 __attribute__((ext_vector_type(2)));
typedef f16 f16x8 __attribute__((ext_vector_type(8)));
typedef float f32x16 __attribute__((ext_vector_type(16)));

// ---------------------------------------------------------------------------
// prep: blocks 0..3: fp32 trapz partial sums for SILU_C / SIG_C
//       blocks 4.. : bake weights into MFMA B-fragment order (f16)
//
// Path1 feature index k (K=448), matching A-frag k = t*16 + (lane>>5)*8 + j:
//   k in [0,256):   ss: u = k>>4, t16 = k&15, feature = s[u]*s[t16]
//   k in [256,448): vv: kk=k-256, i=kk>>6, r8=(kk>>3)&7, c8=kk&7,
//                   feature = v[r8][i]*v[c8][i]  (weight independent of i)
// Output cols n: 0..15 = scal (W_ss0/W_vv0), 16..23 = gates (W_ss1/W_vv1).
// Path2 (K=128): k: a=k>>3, b=k&7, feature = s[a]*v[b][i],
//   weight n<8: (1/16)*(W_sv[a][b][n] + W_vs[b][a][n]).
// B-frag layout (32x32x16): B[k=(lane>>5)*8+j][n=lane&31]; flat index
//   [t][lane][j] = t*512 + lane*8 + j.
// ---------------------------------------------------------------------------
__global__ void prep(const float* __restrict__ wss0, const float* __restrict__ wvv0,
                     const float* __restrict__ wss1, const float* __restrict__ wvv1,
                     const float* __restrict__ wsv,  const float* __restrict__ wvs,
                     float* __restrict__ partials,
                     f16* __restrict__ b1, f16* __restrict__ b2)
{
    const int b = blockIdx.x;
    const int t = threadIdx.x;
    if (b < 4) {
        float ls = 0.f, lg = 0.f;
        for (int i = b * 256 + t; i < NPTS; i += 1024) {
            float xv  = -12.0f + 24.0f * ((float)i / 200000.0f);
            float pdf = __expf(-0.5f * xv * xv) * 0.39894228040143267794f;
            float sg  = 1.0f / (1.0f + __expf(-xv));
            float si  = xv * sg;
            float wt  = (i == 0 || i == NPTS - 1) ? 0.5f : 1.0f;
            ls = fmaf(wt * si * si, pdf, ls);
            lg = fmaf(wt * sg * sg, pdf, lg);
        }
        __shared__ float r1[256], r2[256];
        r1[t] = ls; r2[t] = lg;
        __syncthreads();
        for (int st = 128; st > 0; st >>= 1) {
            if (t < st) { r1[t] += r1[t + st]; r2[t] += r2[t + st]; }
            __syncthreads();
        }
        if (t == 0) { partials[b] = r1[0]; partials[4 + b] = r2[0]; }
    } else {
        const int gid = (b - 4) * 256 + t;
        const float CSC  = 0.05590169943749474241f;                       // 1/sqrt(320)
        const float CSC3 = 0.05590169943749474241f / 1.7320508075688772935f;
        if (gid < 14336) {                      // B1: [28][64][8]
            const int e = gid;
            const int tt   = e >> 9;
            const int lane = (e >> 3) & 63;
            const int j    = e & 7;
            const int n    = lane & 31;
            const int hf   = lane >> 5;
            const int k    = tt * 16 + hf * 8 + j;
            float val = 0.f;
            if (k < 256) {
                const int u = k >> 4, t16 = k & 15;
                if (n < 16)      val = CSC * wss0[(u * 16 + t16) * 16 + n];
                else if (n < 24) val = CSC * wss1[(u * 16 + t16) * 8 + (n - 16)];
            } else {
                const int kk = k - 256;
                const int r8 = (kk >> 3) & 7, c8 = kk & 7;
                if (n < 16)      val = CSC3 * wvv0[(r8 * 8 + c8) * 16 + n];
                else if (n < 24) val = CSC3 * wvv1[(r8 * 8 + c8) * 8 + (n - 16)];
            }
            b1[e] = (f16)val;
        } else if (gid < 18432) {               // B2: [8][64][8]
            const int e = gid - 14336;
            const int tt   = e >> 9;
            const int lane = (e >> 3) & 63;
            const int j    = e & 7;
            const int n    = lane & 31;
            const int hf   = lane >> 5;
            const int k    = tt * 16 + hf * 8 + j;
            const int a = k >> 3, bb = k & 7;
            float val = 0.f;
            if (n < 8)
                val = 0.0625f * (wsv[(a * 8 + bb) * 8 + n] + wvs[(bb * 16 + a) * 8 + n]);
            b2[e] = (f16)val;
        }
    }
}

// ---------------------------------------------------------------------------
// Main kernel: one wave per 32-row tile (grid-stride). No LDS, no barriers.
// A-fragments generated in-register from the lane's own row (lane&31 = row,
// lane>>5 = K-half); B-fragments persistent in VGPRs across the whole loop.
// 52 MFMAs (32x32x16 f16) per 32-row tile; fp32 accumulation.
// C-layout: col = lane&31, row = (reg&3) + 8*(reg>>2) + 4*(lane>>5).
// ---------------------------------------------------------------------------
__global__ __launch_bounds__(256, 2) void seg_main(
    const float* __restrict__ x,
    const f16* __restrict__ b1,       // [28][64][8]
    const f16* __restrict__ b2,       // [8][64][8]
    const float* __restrict__ partials,
    float* __restrict__ out, int n, int nchunks)
{
    const int lane = threadIdx.x & 63;
    const int wid  = threadIdx.x >> 6;
    const int col  = lane & 31;
    const int hf   = lane >> 5;

    // ---- persistent B-fragments (loaded once, coalesced dwordx4) ----
    f16x8 B1[28];
    const f16x8* b1v = (const f16x8*)b1;
#pragma unroll
    for (int t = 0; t < 28; ++t) B1[t] = b1v[t * 64 + lane];
    f16x8 B2f[8];
    const f16x8* b2v = (const f16x8*)b2;
#pragma unroll
    for (int t = 0; t < 8; ++t) B2f[t] = b2v[t * 64 + lane];

    const float dx = 24.0f / 200000.0f;
    const float silu_c = rsqrtf((partials[0] + partials[1] + partials[2] + partials[3]) * dx);
    const float sig_c  = rsqrtf((partials[4] + partials[5] + partials[6] + partials[7]) * dx);

    for (int chunk = blockIdx.x * 4 + wid; chunk < nchunks; chunk += gridDim.x * 4) {
        const int row  = chunk * 32 + col;
        const int lrow = (row < n) ? row : (n - 1);

        // ---- load row, convert to f16 register vectors ----
        f16x2 s2[8];        // s2[a] = {s[2a], s[2a+1]}
        f16x2 vc[3][4];     // vc[i][m] = {v[2m][i], v[2m+1][i]}
        {
            float xr[40] __attribute__((aligned(16)));
            const float4* p4 = (const float4*)(x + (size_t)lrow * 40);
#pragma unroll
            for (int q = 0; q < 10; ++q) ((float4*)xr)[q] = p4[q];
#pragma unroll
            for (int a = 0; a < 8; ++a) { s2[a].x = (f16)xr[2 * a]; s2[a].y = (f16)xr[2 * a + 1]; }
#pragma unroll
            for (int i = 0; i < 3; ++i)
#pragma unroll
                for (int m = 0; m < 4; ++m) {
                    vc[i][m].x = (f16)xr[16 + 3 * (2 * m) + i];
                    vc[i][m].y = (f16)xr[16 + 3 * (2 * m + 1) + i];
                }
        }
        // lane's K-half of s: elements hf*8 .. hf*8+7
        f16x2 shp[4];
#pragma unroll
        for (int m = 0; m < 4; ++m) shp[m] = hf ? s2[4 + m] : s2[m];

        union { f16x2 h[4]; f16x8 v; } A;
        f32x16 acc1;
#pragma unroll
        for (int r = 0; r < 16; ++r) acc1[r] = 0.f;

        // ---- path1 ss: ksteps t=0..15, feature_j = s[t] * s[hf*8+j] ----
#pragma unroll
        for (int t = 0; t < 16; ++t) {
            f16 sv = (t & 1) ? s2[t >> 1].y : s2[t >> 1].x;   // compile-time select
            f16x2 su2; su2.x = sv; su2.y = sv;
#pragma unroll
            for (int m = 0; m < 4; ++m) A.h[m] = su2 * shp[m];
            acc1 = __builtin_amdgcn_mfma_f32_32x32x16_f16(A.v, B1[t], acc1, 0, 0, 0);
        }
        // ---- path1 vv: ksteps tt=0..11; i = tt>>2, u = 2*(tt&3)+hf ----
#pragma unroll
        for (int tt = 0; tt < 12; ++tt) {
            const int i   = tt >> 2;
            const int ttm = tt & 3;
            f16x2 pr = vc[i][ttm];
            f16 sv = hf ? pr.y : pr.x;
            f16x2 su2; su2.x = sv; su2.y = sv;
#pragma unroll
            for (int m = 0; m < 4; ++m) A.h[m] = su2 * vc[i][m];
            acc1 = __builtin_amdgcn_mfma_f32_32x32x16_f16(A.v, B1[16 + tt], acc1, 0, 0, 0);
        }

        // ---- epilogue path1: silu on cols 0..15, gates on cols 16..23 ----
        float gall[16];
#pragma unroll
        for (int r = 0; r < 16; ++r) {
            float val = acc1[r];
            float sgm = 1.0f / (1.0f + __expf(-val));
            gall[r] = sig_c * sgm;
            const int z  = (r & 3) + 8 * (r >> 2) + 4 * hf;
            const int zr = chunk * 32 + z;
            if (col < 16 && zr < n)
                out[(size_t)zr * 40 + col] = silu_c * val * sgm;
        }
        // gate(z, w) lives at col 16+w; pull it to col w via lane+16 shuffle
        float gm[16];
#pragma unroll
        for (int r = 0; r < 16; ++r) gm[r] = __shfl(gall[r], (lane + 16) & 63, 64);

        // ---- path2: per component i, M-row = z, N-col = w (0..7) ----
#pragma unroll
        for (int i = 0; i < 3; ++i) {
            f32x16 acc2;
#pragma unroll
            for (int r = 0; r < 16; ++r) acc2[r] = 0.f;
#pragma unroll
            for (int t2 = 0; t2 < 8; ++t2) {        // a = 2*t2 + hf
                f16x2 pr = s2[t2];
                f16 sv = hf ? pr.y : pr.x;
                f16x2 su2; su2.x = sv; su2.y = sv;
#pragma unroll
                for (int m = 0; m < 4; ++m) A.h[m] = su2 * vc[i][m];
                acc2 = __builtin_amdgcn_mfma_f32_32x32x16_f16(A.v, B2f[t2], acc2, 0, 0, 0);
            }
            if (col < 8) {
#pragma unroll
                for (int r = 0; r < 16; ++r) {
                    const int z  = (r & 3) + 8 * (r >> 2) + 4 * hf;
                    const int zr = chunk * 32 + z;
                    if (zr < n)
                        out[(size_t)zr * 40 + 16 + col * 3 + i] = gm[r] * acc2[r];
                }
            }
        }
    }
}

// ---------------------------------------------------------------------------
extern "C" void kernel_launch(void* const* d_in, const int* in_sizes, int n_in,
                              void* d_out, int out_size, void* d_ws, size_t ws_size,
                              hipStream_t stream)
{
    (void)n_in; (void)out_size; (void)ws_size;
    const float* x    = (const float*)d_in[0];
    const float* wss0 = (const float*)d_in[1];
    const float* wvv0 = (const float*)d_in[2];
    const float* wss1 = (const float*)d_in[3];
    const float* wvv1 = (const float*)d_in[4];
    const float* wsv  = (const float*)d_in[5];
    const float* wvs  = (const float*)d_in[6];
    float* out = (float*)d_out;
    const int n = in_sizes[0] / 40;
    const int nchunks = (n + 31) / 32;

    char* ws = (char*)d_ws;
    float* partials = (float*)(ws + 0);        // 8 floats
    f16*   b1       = (f16*)(ws + 1024);       // 28*64*8 f16 = 28672 B
    f16*   b2       = (f16*)(ws + 30720);      // 8*64*8 f16  = 8192 B

    hipLaunchKernelGGL(prep, dim3(76), dim3(256), 0, stream,
                       wss0, wvv0, wss1, wvv1, wsv, wvs, partials, b1, b2);
    hipLaunchKernelGGL(seg_main, dim3(512), dim3(256), 0, stream,
                       x, b1, b2, partials, out, n, nchunks);
}